// Round 11
// baseline (119.130 us; speedup 1.0000x reference)
//
#include <hip/hip_runtime.h>

constexpr int D  = 128;   // feature dim (= H*F)
constexpr int NH = 4;     // heads
constexpr int NF = 32;    // features per head

typedef __attribute__((ext_vector_type(8))) short bfrag;   // 8 bf16 = 4 VGPR
typedef __attribute__((ext_vector_type(4))) float ffrag;   // 4 f32 acc

// bf16 RNE helpers
__device__ __forceinline__ unsigned short bf16h(float x) {
    unsigned u = __float_as_uint(x);
    u += 0x7fffu + ((u >> 16) & 1u);
    return (unsigned short)(u >> 16);
}
__device__ __forceinline__ float bf16tof(unsigned short h) {
    return __uint_as_float(((unsigned)h) << 16);
}

// async global->LDS, 16B per lane: LDS dst = base + lane*16 (wave-uniform base),
// global src = per-lane address. Our fragment-ordered chunks are exactly this
// shape (chunk = 64 lanes x 16B contiguous on both sides).
__device__ __forceinline__ void gload_lds16(const unsigned short* g, unsigned short* l)
{
    __builtin_amdgcn_global_load_lds(
        (const __attribute__((address_space(1))) void*)g,
        (__attribute__((address_space(3))) void*)l, 16, 0, 0);
}

// ---- launch 1: wsplit (blocks 0..15) + zero counters (blocks 16..) ----
// wsplit output: 1KB chunks indexed ((L*2+plane)*32 + ctg*4 + ks); chunk[lane][i]
// = plane(W[ks*32 + (lane>>4)*8 + i][ctg*16 + (lane&15)]).
__global__ __launch_bounds__(256) void prep_kernel(
    const float* __restrict__ W1, const float* __restrict__ W2,
    unsigned short* __restrict__ wt, int* __restrict__ cnt, int nz)
{
    if (blockIdx.x < 16) {
        const int L  = blockIdx.x >> 3;
        const int ct = blockIdx.x & 7;
        const float* W = L ? W2 : W1;
        const int ks   = threadIdx.x >> 6;
        const int lane = threadIdx.x & 63;
        const int lg = lane >> 4, lc = lane & 15;
        unsigned short* Hp = wt + ((size_t)(L * 2 + 0) * 32 + ct * 4 + ks) * 512 + lane * 8;
        unsigned short* Lp = wt + ((size_t)(L * 2 + 1) * 32 + ct * 4 + ks) * 512 + lane * 8;
        #pragma unroll
        for (int i = 0; i < 8; ++i) {
            const int k = ks * 32 + lg * 8 + i;
            const int c = ct * 16 + lc;
            const float v = W[(size_t)k * 128 + c];
            const unsigned short hh = bf16h(v);
            Hp[i] = hh;
            Lp[i] = bf16h(v - bf16tof(hh));
        }
    } else {
        const int i4 = ((blockIdx.x - 16) * 256 + threadIdx.x) * 4;
        if (i4 + 3 < nz) {
            *(int4*)&cnt[i4] = {0, 0, 0, 0};
        } else if (i4 < nz) {
            for (int i = i4; i < nz; ++i) cnt[i] = 0;
        }
    }
}

// ---- launch 2: canonical LDS-staged MFMA MLP + histogram tail ----
// R10 model: ~128 B-frag global loads/wave, each an exposed ~300cy L2 round
// trip (compiler register-recycles the B path regardless of source structure).
// Fix: B never touches VGPRs on the global path — global_load_lds stages one
// layer's 64KB (64 chunks) per block, inner loop reads B via ds_read_b128
// (~120cy, fine-grained lgkmcnt scheduling). h1 scratch overlays the dead W
// region between barriers -> LDS stays 64KB -> 2 blocks/CU.
__global__ __launch_bounds__(256, 2) void mlp_hist_kernel(
    const float* __restrict__ X,
    const unsigned short* __restrict__ WF,
    const float* __restrict__ b1, const float* __restrict__ g1, const float* __restrict__ be1,
    const float* __restrict__ b2, const float* __restrict__ g2, const float* __restrict__ be2,
    unsigned short* __restrict__ Q, int N,
    const int* __restrict__ recv, int* __restrict__ cnt, int E, int mlpBlocks)
{
    __shared__ unsigned short Wlds[32768];     // 64KB: one layer (hi 0..31, lo 32..63)

    if (blockIdx.x >= mlpBlocks) {
        // ---- histogram role ----
        const int tid0   = (blockIdx.x - mlpBlocks) * 256 + threadIdx.x;
        const int stride = (gridDim.x - mlpBlocks) * 256;
        for (int i = tid0; i < E; i += stride) atomicAdd(&cnt[recv[i]], 1);
        return;
    }

    constexpr int PW = 132;                    // u32 pitch for h1 scratch
    const int tid  = threadIdx.x;
    const int lane = tid & 63;
    const int wave = tid >> 6;
    const int lc   = lane & 15;
    const int lg   = lane >> 4;
    const int n0w  = blockIdx.x * 64 + wave * 16;   // tail waves stay (barriers!)

    bfrag ah[4], al[4];
    ffrag acc[8];

    // ---- A-frags layer 1: issue early (overlaps W1 staging) ----
    {
        const int row = n0w + lc;
        const int rowx = (row < N) ? row : (N - 1);
        const float* xr = X + (size_t)rowx * 128 + lg * 8;
        #pragma unroll
        for (int ks = 0; ks < 4; ++ks) {
            const float4 a = *(const float4*)&xr[ks * 32];
            const float4 b = *(const float4*)&xr[ks * 32 + 4];
            const float f[8] = {a.x, a.y, a.z, a.w, b.x, b.y, b.z, b.w};
            #pragma unroll
            for (int i = 0; i < 8; ++i) {
                const unsigned short hh = bf16h(f[i]);
                ah[ks][i] = (short)hh;
                al[ks][i] = (short)bf16h(f[i] - bf16tof(hh));
            }
        }
    }

    // ---- hoist LN params ----
    float b1v[8], g1v[8], t1v[8], b2v[8], g2v[8], t2v[8];
    #pragma unroll
    for (int ct = 0; ct < 8; ++ct) {
        const int col = ct * 16 + lc;
        b1v[ct] = b1[col]; g1v[ct] = g1[col]; t1v[ct] = be1[col];
        b2v[ct] = b2[col]; g2v[ct] = g2[col]; t2v[ct] = be2[col];
    }

// stage one layer's 64 chunks (1KB each): wave stages chunks wave*16..wave*16+15
#define STAGE_LAYER(Lbase)                                                     \
    {                                                                          \
        _Pragma("unroll")                                                      \
        for (int i_ = 0; i_ < 16; ++i_) {                                      \
            const int ch_ = wave * 16 + i_;                                    \
            gload_lds16(WF + ((size_t)(Lbase) + ch_) * 512 + lane * 8,         \
                        &Wlds[ch_ * 512]);                                     \
        }                                                                      \
    }

// GEMM over one staged layer: B from LDS (hi chunks 0..31, lo 32..63)
#define GEMM_LDS()                                                             \
    _Pragma("unroll")                                                          \
    for (int ct_ = 0; ct_ < 8; ++ct_) {                                        \
        const unsigned short* bh_ = &Wlds[(ct_ * 4) * 512 + lane * 8];         \
        const unsigned short* bl_ = &Wlds[(32 + ct_ * 4) * 512 + lane * 8];    \
        ffrag aH_ = (ffrag){0.f,0.f,0.f,0.f}, aX_ = (ffrag){0.f,0.f,0.f,0.f};  \
        _Pragma("unroll")                                                      \
        for (int ks_ = 0; ks_ < 4; ++ks_) {                                    \
            const bfrag bh = *(const bfrag*)(bh_ + ks_ * 512);                 \
            const bfrag bl = *(const bfrag*)(bl_ + ks_ * 512);                 \
            aH_ = __builtin_amdgcn_mfma_f32_16x16x32_bf16(ah[ks_], bh, aH_, 0, 0, 0); \
            aX_ = __builtin_amdgcn_mfma_f32_16x16x32_bf16(ah[ks_], bl, aX_, 0, 0, 0); \
            aX_ = __builtin_amdgcn_mfma_f32_16x16x32_bf16(al[ks_], bh, aX_, 0, 0, 0); \
        }                                                                      \
        acc[ct_] = aH_ + aX_;                                                  \
    }

    // ================= layer 1 =================
    STAGE_LAYER(0)
    __syncthreads();                 // waitcnt(0) + barrier: W1 resident

    GEMM_LDS()
    __syncthreads();                 // all W1 reads done (scratch overlays W region)

    // ---- LN1 + ReLU -> packed hi|lo u32 into per-wave scratch (overlay) ----
    unsigned* scr = (unsigned*)Wlds + wave * (16 * PW);   // 8448B/wave, 33792B total
    #pragma unroll
    for (int j = 0; j < 4; ++j) {
        float t[8], s = 0.f, ss = 0.f;
        #pragma unroll
        for (int ct = 0; ct < 8; ++ct) {
            t[ct] = acc[ct][j] + b1v[ct];
            s += t[ct]; ss += t[ct] * t[ct];
        }
        #pragma unroll
        for (int off = 1; off <= 8; off <<= 1) {
            s  += __shfl_xor(s,  off, 16);
            ss += __shfl_xor(ss, off, 16);
        }
        const float mu   = s * (1.f / 128.f);
        const float var  = fmaxf(ss * (1.f / 128.f) - mu * mu, 0.f);
        const float rstd = rsqrtf(var + 1e-6f);
        const int row = lg * 4 + j;
        #pragma unroll
        for (int ct = 0; ct < 8; ++ct) {
            const float o = fmaxf((t[ct] - mu) * rstd * g1v[ct] + t1v[ct], 0.f);
            const unsigned short hh = bf16h(o);
            const unsigned short ll = bf16h(o - bf16tof(hh));
            scr[row * PW + ct * 16 + lc] = (unsigned)hh | ((unsigned)ll << 16);
        }
    }

    // wave-local fence before cross-lane scratch reads (rule #18: + sched fence)
    asm volatile("s_waitcnt lgkmcnt(0)" ::: "memory");
    __builtin_amdgcn_sched_barrier(0);

    // ---- A-frags layer 2 from scratch (row = lc, k = ks*32+lg*8+i) ----
    #pragma unroll
    for (int ks = 0; ks < 4; ++ks) {
        const uint4 r0 = *(const uint4*)&scr[lc * PW + ks * 32 + lg * 8];
        const uint4 r1 = *(const uint4*)&scr[lc * PW + ks * 32 + lg * 8 + 4];
        const unsigned rr[8] = {r0.x, r0.y, r0.z, r0.w, r1.x, r1.y, r1.z, r1.w};
        #pragma unroll
        for (int i = 0; i < 8; ++i) {
            ah[ks][i] = (short)(rr[i] & 0xffffu);
            al[ks][i] = (short)(rr[i] >> 16);
        }
    }
    __syncthreads();                 // all scratch reads done before W2 staging

    // ================= layer 2 =================
    STAGE_LAYER(64)
    __syncthreads();                 // W2 resident

    GEMM_LDS()

#undef GEMM_LDS
#undef STAGE_LAYER

    // ---- LN2 + ReLU -> bf16 q (global) ----
    #pragma unroll
    for (int j = 0; j < 4; ++j) {
        float t[8], s = 0.f, ss = 0.f;
        #pragma unroll
        for (int ct = 0; ct < 8; ++ct) {
            t[ct] = acc[ct][j] + b2v[ct];
            s += t[ct]; ss += t[ct] * t[ct];
        }
        #pragma unroll
        for (int off = 1; off <= 8; off <<= 1) {
            s  += __shfl_xor(s,  off, 16);
            ss += __shfl_xor(ss, off, 16);
        }
        const float mu   = s * (1.f / 128.f);
        const float var  = fmaxf(ss * (1.f / 128.f) - mu * mu, 0.f);
        const float rstd = rsqrtf(var + 1e-6f);
        const int grow = n0w + lg * 4 + j;
        if (grow < N) {
            #pragma unroll
            for (int ct = 0; ct < 8; ++ct) {
                const float o = fmaxf((t[ct] - mu) * rstd * g2v[ct] + t2v[ct], 0.f);
                Q[(size_t)grow * 128 + ct * 16 + lc] = bf16h(o);
            }
        }
    }
}

// ---- CSR build: per-1024-chunk exclusive scan ----
__global__ __launch_bounds__(256) void scan_blocks_kernel(
    const int* __restrict__ cnt, int* __restrict__ rowptr,
    int* __restrict__ bsum, int N)
{
    __shared__ int lds[256];
    const int tid = threadIdx.x;
    const int base = blockIdx.x * 1024 + tid * 4;
    int v0 = (base + 0 < N) ? cnt[base + 0] : 0;
    int v1 = (base + 1 < N) ? cnt[base + 1] : 0;
    int v2 = (base + 2 < N) ? cnt[base + 2] : 0;
    int v3 = (base + 3 < N) ? cnt[base + 3] : 0;
    const int tsum = v0 + v1 + v2 + v3;
    lds[tid] = tsum;
    __syncthreads();
    for (int off = 1; off < 256; off <<= 1) {
        int t = (tid >= off) ? lds[tid - off] : 0;
        __syncthreads();
        lds[tid] += t;
        __syncthreads();
    }
    int run = lds[tid] - tsum;
    if (base + 0 < N) rowptr[base + 0] = run;
    run += v0;
    if (base + 1 < N) rowptr[base + 1] = run;
    run += v1;
    if (base + 2 < N) rowptr[base + 2] = run;
    run += v2;
    if (base + 3 < N) rowptr[base + 3] = run;
    if (tid == 255) bsum[blockIdx.x] = lds[255];
}

// ---- CSR build: scan block sums ----
__global__ __launch_bounds__(256) void scan_top_kernel(int* bsum, int nb)
{
    __shared__ int lds[256];
    const int tid = threadIdx.x;
    int v = (tid < nb) ? bsum[tid] : 0;
    lds[tid] = v;
    __syncthreads();
    for (int off = 1; off < 256; off <<= 1) {
        int t = (tid >= off) ? lds[tid - off] : 0;
        __syncthreads();
        lds[tid] += t;
        __syncthreads();
    }
    if (tid < nb) bsum[tid] = lds[tid] - v;
}

// ---- CSR build: add chunk offsets ----
__global__ __launch_bounds__(256) void scan_add_kernel(
    int* __restrict__ rowptr, int* __restrict__ cursor,
    const int* __restrict__ bsum, int N, int E)
{
    int i = blockIdx.x * blockDim.x + threadIdx.x;
    if (i < N) {
        int v = rowptr[i] + bsum[i >> 10];
        rowptr[i] = v;
        cursor[i] = v;
    }
    if (i == 0) rowptr[N] = E;
}

// ---- CSR build: bucket-fill sorted sender ids ----
__global__ __launch_bounds__(256) void fill_kernel(
    const int* __restrict__ senders, const int* __restrict__ receivers,
    int* __restrict__ cursor, int* __restrict__ ssend, int E)
{
    int e = blockIdx.x * blockDim.x + threadIdx.x;
    if (e < E) {
        int r = receivers[e];
        int pos = atomicAdd(&cursor[r], 1);
        ssend[pos] = senders[e];
    }
}

// ---- fused per-node attention (bf16 q) ----
__global__ __launch_bounds__(256) void node_attn_kernel(
    const unsigned short* __restrict__ q, const int* __restrict__ rowptr,
    const int* __restrict__ ssend, float* __restrict__ out, int N)
{
    const int lane = threadIdx.x & 63;
    const int hl   = lane & 31;
    const int half = lane >> 5;
    const int wid  = (blockIdx.x * blockDim.x + threadIdx.x) >> 6;
    const int nw   = (gridDim.x * blockDim.x) >> 6;

    for (int n = wid; n < N; n += nw) {
        const uint2 braw = *(const uint2*)&q[(size_t)n * D + hl * 4];
        const float b0 = __uint_as_float(braw.x << 16);
        const float b1 = __uint_as_float(braw.x & 0xffff0000u);
        const float b2 = __uint_as_float(braw.y << 16);
        const float b3 = __uint_as_float(braw.y & 0xffff0000u);

        const int beg = rowptr[n], end = rowptr[n + 1];
        float m = -1e30f, l = 0.f;
        float c0 = 0.f, c1 = 0.f, c2 = 0.f, c3 = 0.f;

        int j = beg + half;
        uint2 raw = {0u, 0u};
        if (j < end)
            raw = *(const uint2*)&q[(size_t)ssend[j] * D + hl * 4];
        for (; j < end; j += 2) {
            const uint2 cur = raw;
            if (j + 2 < end)
                raw = *(const uint2*)&q[(size_t)ssend[j + 2] * D + hl * 4];
            const float a0 = __uint_as_float(cur.x << 16);
            const float a1 = __uint_as_float(cur.x & 0xffff0000u);
            const float a2 = __uint_as_float(cur.y << 16);
            const float a3 = __uint_as_float(cur.y & 0xffff0000u);
            float p = a0 * b0 + a1 * b1 + a2 * b2 + a3 * b3;
            p += __shfl_xor(p, 1);
            p += __shfl_xor(p, 2);
            p += __shfl_xor(p, 4);
            const float logit = p * 0.17677669529663687f;   // 1/sqrt(32)
            const float nm = fmaxf(m, logit);
            const float sc = __expf(m - nm);
            const float u  = __expf(logit - nm);
            l  = l * sc + u;
            c0 = c0 * sc + u * a0;
            c1 = c1 * sc + u * a1;
            c2 = c2 * sc + u * a2;
            c3 = c3 * sc + u * a3;
            m = nm;
        }

        const float om  = __shfl_xor(m, 32);
        const float ol  = __shfl_xor(l, 32);
        const float oc0 = __shfl_xor(c0, 32);
        const float oc1 = __shfl_xor(c1, 32);
        const float oc2 = __shfl_xor(c2, 32);
        const float oc3 = __shfl_xor(c3, 32);
        const float nm = fmaxf(m, om);
        const float s0 = __expf(m - nm), s1 = __expf(om - nm);
        const float lt = l * s0 + ol * s1;
        const float inv = (lt > 0.f) ? (1.f / lt) : 0.f;
        float r0 = fmaxf((c0 * s0 + oc0 * s1) * inv, 0.f);
        float r1 = fmaxf((c1 * s0 + oc1 * s1) * inv, 0.f);
        float r2 = fmaxf((c2 * s0 + oc2 * s1) * inv, 0.f);
        float r3 = fmaxf((c3 * s0 + oc3 * s1) * inv, 0.f);

        r0 += __shfl_xor(r0, 8);  r0 += __shfl_xor(r0, 16);
        r1 += __shfl_xor(r1, 8);  r1 += __shfl_xor(r1, 16);
        r2 += __shfl_xor(r2, 8);  r2 += __shfl_xor(r2, 16);
        r3 += __shfl_xor(r3, 8);  r3 += __shfl_xor(r3, 16);
        if (lane < 8) {
            float4 o = {0.25f * r0, 0.25f * r1, 0.25f * r2, 0.25f * r3};
            *(float4*)&out[(size_t)n * NF + lane * 4] = o;
        }
    }
}

extern "C" void kernel_launch(void* const* d_in, const int* in_sizes, int n_in,
                              void* d_out, int out_size, void* d_ws, size_t ws_size,
                              hipStream_t stream)
{
    const float* nodes = (const float*)d_in[0];
    const float* W1    = (const float*)d_in[1];
    const float* b1    = (const float*)d_in[2];
    const float* g1    = (const float*)d_in[3];
    const float* be1   = (const float*)d_in[4];
    const float* W2    = (const float*)d_in[5];
    const float* b2    = (const float*)d_in[6];
    const float* g2    = (const float*)d_in[7];
    const float* be2   = (const float*)d_in[8];
    const int* senders   = (const int*)d_in[9];
    const int* receivers = (const int*)d_in[10];

    const int N = in_sizes[0] / D;
    const int E = in_sizes[9];
    float* out = (float*)d_out;

    char* ws = (char*)d_ws;
    unsigned short* qb = (unsigned short*)ws; ws += (size_t)N * D * 2;
    unsigned short* wt = (unsigned short*)ws; ws += 4 * 128 * 128 * 2;
    int* cnt      = (int*)ws;    ws += (size_t)N * 4;
    int* rowptr   = (int*)ws;    ws += (size_t)(N + 2) * 4;
    int* cursor   = (int*)ws;    ws += (size_t)N * 4;
    int* bsum     = (int*)ws;    ws += 256 * 4;
    int* ssend    = (int*)ws;    ws += (size_t)E * 4;

    const int zb = (N + 1023) / 1024;
    const int mlpBlocks = (N + 63) / 64;
    const int nb = (N + 1023) / 1024;

    // 1: weight split + counter zero
    prep_kernel<<<16 + zb, 256, 0, stream>>>(W1, W2, wt, cnt, N);

    // 2: LDS-staged MFMA MLP + edge histogram (tail blocks)
    mlp_hist_kernel<<<mlpBlocks + 128, 256, 0, stream>>>(
        nodes, wt, b1, g1, be1, b2, g2, be2, qb, N,
        receivers, cnt, E, mlpBlocks);

    // 3-5: CSR scan
    scan_blocks_kernel<<<nb, 256, 0, stream>>>(cnt, rowptr, bsum, N);
    scan_top_kernel<<<1, 256, 0, stream>>>(bsum, nb);
    scan_add_kernel<<<(N + 255) / 256, 256, 0, stream>>>(rowptr, cursor, bsum, N, E);

    // 6: bucket-fill receiver-sorted sender list
    fill_kernel<<<(E + 255) / 256, 256, 0, stream>>>(senders, receivers, cursor, ssend, E);

    // 7: fused attention + epilogue
    node_attn_kernel<<<(N + 3) / 4, 256, 0, stream>>>(qb, rowptr, ssend, out, N);
}